// Round 7
// baseline (820.175 us; speedup 1.0000x reference)
//
#include <hip/hip_runtime.h>
#include <cstdint>
#include <cstddef>

// GraphCluster: 3-layer GCN + assign head, 100K nodes / 1.6M edges.
// R1: hierarchical scan. R2: f16-MFMA GEMMs, dinv folded into epilogue.
// R3: f16 intermediate pipeline. R4 bucketed fill REVERTED (few hot cursors
// serialize at ~185ns/atomic). R5: agg 4-edge x half8. R6: agg unroll-8
// (8 outstanding 16B gathers/lane; agg is latency-bound at 34% HBM).

#define SCAN_CHUNK 2048

typedef _Float16 half8 __attribute__((ext_vector_type(8)));
typedef _Float16 half4 __attribute__((ext_vector_type(4)));
typedef float floatx4 __attribute__((ext_vector_type(4)));

// ---------------------------------------------------------------- CSR build
__global__ __launch_bounds__(256) void count_edges_k(const int* __restrict__ dst, int E,
                                                     int* __restrict__ cnt) {
  int idx = blockIdx.x * blockDim.x + threadIdx.x;
  int stride = gridDim.x * blockDim.x;
  for (int e = idx; e < E; e += stride) atomicAdd(&cnt[dst[e]], 1);
}

__global__ __launch_bounds__(256) void dinv_k(const int* __restrict__ cnt,
                                              float* __restrict__ dinv, int N) {
  int i = blockIdx.x * blockDim.x + threadIdx.x;
  if (i < N) dinv[i] = rsqrtf((float)(cnt[i] + 1));  // +1 self-loop
}

__global__ __launch_bounds__(256) void scan_partial_k(const int* __restrict__ cnt, int N,
                                                      int* __restrict__ bsum) {
  __shared__ int red[256];
  int b = blockIdx.x, t = threadIdx.x;
  int base = b * SCAN_CHUNK + t * 8;
  int s = 0;
#pragma unroll
  for (int i = 0; i < 8; ++i) {
    int idx = base + i;
    if (idx < N) s += cnt[idx];
  }
  red[t] = s;
  __syncthreads();
  for (int off = 128; off > 0; off >>= 1) {
    if (t < off) red[t] += red[t + off];
    __syncthreads();
  }
  if (t == 0) bsum[b] = red[0];
}

__global__ __launch_bounds__(64) void scan_bsum_k(int* __restrict__ bsum, int NB) {
  int lane = threadIdx.x;
  int per = (NB + 63) >> 6;
  int beg = lane * per;
  int end = min(beg + per, NB);
  int s = 0;
  for (int i = beg; i < end; ++i) s += bsum[i];
  int ps = s;
  for (int off = 1; off < 64; off <<= 1) {
    int u = __shfl_up(ps, off, 64);
    if (lane >= off) ps += u;
  }
  int run = ps - s;
  for (int i = beg; i < end; ++i) {
    int c = bsum[i];
    bsum[i] = run;
    run += c;
  }
}

__global__ __launch_bounds__(256) void scan_apply_k(const int* __restrict__ cnt,
                                                    const int* __restrict__ bsum_excl, int N,
                                                    int* __restrict__ rowptr,
                                                    int* __restrict__ cursor, int E) {
  __shared__ int wave_sums[4];
  int b = blockIdx.x, t = threadIdx.x;
  int base = b * SCAN_CHUNK + t * 8;
  int v[8];
  int s = 0;
#pragma unroll
  for (int i = 0; i < 8; ++i) {
    int idx = base + i;
    v[i] = (idx < N) ? cnt[idx] : 0;
    s += v[i];
  }
  int lane = t & 63, wave = t >> 6;
  int ps = s;
  for (int off = 1; off < 64; off <<= 1) {
    int u = __shfl_up(ps, off, 64);
    if (lane >= off) ps += u;
  }
  if (lane == 63) wave_sums[wave] = ps;
  __syncthreads();
  int woff = 0;
  for (int w = 0; w < 4; ++w)
    if (w < wave) woff += wave_sums[w];
  int excl = woff + (ps - s) + bsum_excl[b];
#pragma unroll
  for (int i = 0; i < 8; ++i) {
    int idx = base + i;
    if (idx < N) {
      rowptr[idx] = excl;
      cursor[idx] = excl;
      excl += v[i];
    }
  }
  if (b == 0 && t == 0) rowptr[N] = E;
}

__global__ __launch_bounds__(256) void fill_k(const int* __restrict__ src,
                                              const int* __restrict__ dst, int E,
                                              int* __restrict__ cursor, int* __restrict__ col) {
  int idx = blockIdx.x * blockDim.x + threadIdx.x;
  int stride = gridDim.x * blockDim.x;
  for (int e = idx; e < E; e += stride) {
    int d = dst[e];
    int pos = atomicAdd(&cursor[d], 1);
    __builtin_nontemporal_store(src[e], &col[pos]);
  }
}

// ---------------------------------------------------------------- f16 MFMA GEMM
template <bool SIG, bool HIN, bool HOUT, int NT>
__global__ __launch_bounds__(256) void gemm_mfma_k(const void* __restrict__ Av,
                                                   const float* __restrict__ W,
                                                   const float* __restrict__ bias,
                                                   const float* __restrict__ scale,
                                                   void* __restrict__ outv, int N) {
  constexpr int NCOL = NT * 16;
  __shared__ __align__(16) _Float16 Af[64][136];
  __shared__ __align__(16) _Float16 Wf[NCOL][136];
  const int tid = threadIdx.x;
  const int r0 = blockIdx.x * 64;
  if (HIN) {
    const _Float16* A = (const _Float16*)Av;
    for (int idx = tid; idx < 64 * 16; idx += 256) {
      int row = idx >> 4;
      int c8 = (idx & 15) << 3;
      half8 v = {0, 0, 0, 0, 0, 0, 0, 0};
      int gr = r0 + row;
      if (gr < N) v = *(const half8*)(A + (size_t)gr * 128 + c8);
      *(half8*)&Af[row][c8] = v;
    }
  } else {
    const float* A = (const float*)Av;
    for (int idx = tid; idx < 64 * 32; idx += 256) {
      int row = idx >> 5;
      int c4 = (idx & 31) << 2;
      float4 v = make_float4(0.f, 0.f, 0.f, 0.f);
      int gr = r0 + row;
      if (gr < N) v = *(const float4*)(A + (size_t)gr * 128 + c4);
      Af[row][c4 + 0] = (_Float16)v.x;
      Af[row][c4 + 1] = (_Float16)v.y;
      Af[row][c4 + 2] = (_Float16)v.z;
      Af[row][c4 + 3] = (_Float16)v.w;
    }
  }
  for (int idx = tid; idx < 128 * (NCOL / 4); idx += 256) {
    int k = idx / (NCOL / 4);
    int n4 = (idx % (NCOL / 4)) << 2;
    float4 v = *(const float4*)(W + (size_t)k * NCOL + n4);
    Wf[n4 + 0][k] = (_Float16)v.x;
    Wf[n4 + 1][k] = (_Float16)v.y;
    Wf[n4 + 2][k] = (_Float16)v.z;
    Wf[n4 + 3][k] = (_Float16)v.w;
  }
  __syncthreads();
  const int w = tid >> 6, lane = tid & 63;
  const int m = lane & 15, q = lane >> 4;
  floatx4 acc[NT];
#pragma unroll
  for (int t = 0; t < NT; ++t) acc[t] = (floatx4){0.f, 0.f, 0.f, 0.f};
#pragma unroll
  for (int kt = 0; kt < 128; kt += 32) {
    half8 a = *(const half8*)&Af[w * 16 + m][kt + q * 8];
#pragma unroll
    for (int t = 0; t < NT; ++t) {
      half8 b = *(const half8*)&Wf[t * 16 + m][kt + q * 8];
      acc[t] = __builtin_amdgcn_mfma_f32_16x16x32_f16(a, b, acc[t], 0, 0, 0);
    }
  }
#pragma unroll
  for (int r = 0; r < 4; ++r) {
    int row = r0 + w * 16 + q * 4 + r;
    if (row >= N) continue;
    float sc = scale ? scale[row] : 1.f;
#pragma unroll
    for (int t = 0; t < NT; ++t) {
      int colg = t * 16 + m;
      float v = acc[t][r];
      if (bias) v += bias[colg];
      if (SIG) v = 1.f / (1.f + __expf(-v));
      v *= sc;
      if (HOUT)
        ((_Float16*)outv)[(size_t)row * NCOL + colg] = (_Float16)v;
      else
        ((float*)outv)[(size_t)row * NCOL + colg] = v;
    }
  }
}

// ---------------------------------------------------------------- aggregation
// xw (f16, pre-scaled by dinv[row]): out[i] = b + dinv[i]*(xw[i]+sum xw[src]).
// One wave/node; 16 lanes x half8 (16B) cover the row; 4 edge slots
// (j=lane>>4), unrolled 8x -> 8 independent 16B gathers in flight per lane.
__global__ __launch_bounds__(256) void agg128h_k(const _Float16* __restrict__ xw,
                                                 const int* __restrict__ rowptr,
                                                 const int* __restrict__ col,
                                                 const float* __restrict__ dinv,
                                                 const float* __restrict__ bias,
                                                 _Float16* __restrict__ out, int N) {
  int node = blockIdx.x * 4 + (threadIdx.x >> 6);
  if (node >= N) return;
  int lane = threadIdx.x & 63;
  int fl = lane & 15;  // feature chunk (8 f16 = 16B)
  int j = lane >> 4;   // edge slot 0..3
  int beg = rowptr[node];
  int end = rowptr[node + 1];
  const _Float16* base = xw + (size_t)fl * 8;
  float a[8] = {0.f, 0.f, 0.f, 0.f, 0.f, 0.f, 0.f, 0.f};
  int e = beg + j;
  for (; e + 28 < end; e += 32) {
    int s[8];
#pragma unroll
    for (int u = 0; u < 8; ++u) s[u] = col[e + 4 * u];
    half8 v[8];
#pragma unroll
    for (int u = 0; u < 8; ++u) v[u] = *(const half8*)(base + (size_t)s[u] * 128);
#pragma unroll
    for (int f = 0; f < 8; ++f) {
      float t0 = ((float)v[0][f] + (float)v[1][f]) + ((float)v[2][f] + (float)v[3][f]);
      float t1 = ((float)v[4][f] + (float)v[5][f]) + ((float)v[6][f] + (float)v[7][f]);
      a[f] += t0 + t1;
    }
  }
  for (; e + 12 < end; e += 16) {
    int s0 = col[e], s1 = col[e + 4], s2 = col[e + 8], s3 = col[e + 12];
    half8 v0 = *(const half8*)(base + (size_t)s0 * 128);
    half8 v1 = *(const half8*)(base + (size_t)s1 * 128);
    half8 v2 = *(const half8*)(base + (size_t)s2 * 128);
    half8 v3 = *(const half8*)(base + (size_t)s3 * 128);
#pragma unroll
    for (int f = 0; f < 8; ++f)
      a[f] += ((float)v0[f] + (float)v1[f]) + ((float)v2[f] + (float)v3[f]);
  }
  for (; e < end; e += 4) {
    half8 v = *(const half8*)(base + (size_t)col[e] * 128);
#pragma unroll
    for (int f = 0; f < 8; ++f) a[f] += (float)v[f];
  }
  if (j == 0) {  // self-loop term once
    half8 v = *(const half8*)(base + (size_t)node * 128);
#pragma unroll
    for (int f = 0; f < 8; ++f) a[f] += (float)v[f];
  }
#pragma unroll
  for (int f = 0; f < 8; ++f) {
    a[f] += __shfl_xor(a[f], 16, 64);
    a[f] += __shfl_xor(a[f], 32, 64);
  }
  if (j == 0) {
    float di = dinv[node];
    float4 b0 = *(const float4*)(bias + fl * 8);
    float4 b1 = *(const float4*)(bias + fl * 8 + 4);
    half8 o;
    o[0] = (_Float16)fmaf(a[0], di, b0.x);
    o[1] = (_Float16)fmaf(a[1], di, b0.y);
    o[2] = (_Float16)fmaf(a[2], di, b0.z);
    o[3] = (_Float16)fmaf(a[3], di, b0.w);
    o[4] = (_Float16)fmaf(a[4], di, b1.x);
    o[5] = (_Float16)fmaf(a[5], di, b1.y);
    o[6] = (_Float16)fmaf(a[6], di, b1.z);
    o[7] = (_Float16)fmaf(a[7], di, b1.w);
    *(half8*)(out + (size_t)node * 128 + fl * 8) = o;
  }
}

__global__ __launch_bounds__(256) void agg16_k(const float* __restrict__ xw,
                                               const int* __restrict__ rowptr,
                                               const int* __restrict__ col,
                                               const float* __restrict__ dinv,
                                               const float* __restrict__ bias,
                                               float* __restrict__ out, int N) {
  int node = blockIdx.x * 4 + (threadIdx.x >> 6);
  if (node >= N) return;
  int lane = threadIdx.x & 63;
  int f = lane & 15;
  int j = lane >> 4;
  int beg = rowptr[node];
  int end = rowptr[node + 1];
  float acc = 0.f;
  int e = beg + j;
  for (; e + 12 < end; e += 16) {
    float v0 = xw[(size_t)col[e] * 16 + f];
    float v1 = xw[(size_t)col[e + 4] * 16 + f];
    float v2 = xw[(size_t)col[e + 8] * 16 + f];
    float v3 = xw[(size_t)col[e + 12] * 16 + f];
    acc += (v0 + v1) + (v2 + v3);
  }
  for (; e < end; e += 4) acc += xw[(size_t)col[e] * 16 + f];
  acc += __shfl_xor(acc, 16, 64);
  acc += __shfl_xor(acc, 32, 64);
  float o = fmaf(acc + xw[(size_t)node * 16 + f], dinv[node], bias[f]);
  if (j == 0) out[(size_t)node * 16 + f] = o;
}

// ---------------------------------------------------------------- launch
extern "C" void kernel_launch(void* const* d_in, const int* in_sizes, int n_in,
                              void* d_out, int out_size, void* d_ws, size_t ws_size,
                              hipStream_t stream) {
  const int* adj = (const int*)d_in[0];
  const float* X = (const float*)d_in[1];
  const float* fc1_W = (const float*)d_in[2];
  const float* fc1_b = (const float*)d_in[3];
  const float* fc2_W = (const float*)d_in[4];
  const float* fc2_b = (const float*)d_in[5];
  const float* gcn_W = (const float*)d_in[6];
  const float* gcn_b = (const float*)d_in[7];
  const float* assign_W = (const float*)d_in[8];
  const float* assign_b = (const float*)d_in[9];
  const int E = in_sizes[0] / 2;
  const int N = in_sizes[1] / 128;
  const int* src = adj;
  const int* dst = adj + E;

  char* ws = (char*)d_ws;
  size_t off = 0;
  auto alloc = [&](size_t bytes) {
    void* p = ws + off;
    off = (off + bytes + 511) & ~(size_t)511;
    return p;
  };
  _Float16* Ph = (_Float16*)alloc((size_t)N * 128 * 2);  // 25.6 MB
  _Float16* Qh = (_Float16*)alloc((size_t)N * 128 * 2);  // 25.6 MB
  int* cnt = (int*)alloc((size_t)N * 4);
  float* dinv = (float*)alloc((size_t)N * 4);
  int* rowptr = (int*)alloc((size_t)(N + 1) * 4);
  int* cursor = (int*)alloc((size_t)N * 4);
  int* col = (int*)alloc((size_t)E * 4);
  int* bsum = (int*)alloc(4096);
  float* S = (float*)Ph;  // assign xw [N,16] fp32 reuses Ph

  const int NB = (N + SCAN_CHUNK - 1) / SCAN_CHUNK;

  hipMemsetAsync(cnt, 0, (size_t)N * 4, stream);
  count_edges_k<<<2048, 256, 0, stream>>>(dst, E, cnt);
  dinv_k<<<(N + 255) / 256, 256, 0, stream>>>(cnt, dinv, N);
  scan_partial_k<<<NB, 256, 0, stream>>>(cnt, N, bsum);
  scan_bsum_k<<<1, 64, 0, stream>>>(bsum, NB);
  scan_apply_k<<<NB, 256, 0, stream>>>(cnt, bsum, N, rowptr, cursor, E);
  fill_k<<<2048, 256, 0, stream>>>(src, dst, E, cursor, col);

  int gb = (N + 63) / 64;
  int ab = (N + 3) / 4;
  gemm_mfma_k<true, false, true, 8><<<gb, 256, 0, stream>>>(X, fc1_W, fc1_b, nullptr, Ph, N);
  gemm_mfma_k<true, true, true, 8><<<gb, 256, 0, stream>>>(Ph, fc2_W, fc2_b, nullptr, Qh, N);
  for (int l = 0; l < 3; ++l) {
    gemm_mfma_k<false, true, true, 8><<<gb, 256, 0, stream>>>(
        Qh, gcn_W + (size_t)l * 128 * 128, nullptr, dinv, Ph, N);
    agg128h_k<<<ab, 256, 0, stream>>>(Ph, rowptr, col, dinv, gcn_b + (size_t)l * 128, Qh, N);
  }
  gemm_mfma_k<false, true, false, 1><<<gb, 256, 0, stream>>>(Qh, assign_W, nullptr, dinv, S, N);
  agg16_k<<<ab, 256, 0, stream>>>(S, rowptr, col, dinv, assign_b, (float*)d_out, N);
}

// Round 8
// 628.377 us; speedup vs baseline: 1.3052x; 1.3052x over previous
//
#include <hip/hip_runtime.h>
#include <cstdint>
#include <cstddef>

// GraphCluster: 3-layer GCN + assign head, 100K nodes / 1.6M edges.
// R1: hierarchical scan. R2: f16-MFMA GEMMs, dinv folded into epilogue.
// R3: f16 intermediates. R4 bucketed fill REVERTED (hot-cursor atomics
// serialize ~185ns each). R6 agg unroll-8 REVERTED (avg deg 16 -> loop never
// taken, +52us). R7: scan-based two-level counting-sort CSR build — zero
// contended atomics, line-local writes (was 109MB writeback, now ~15MB);
// rowptr/dinv produced inside P2 (count_edges_k + cnt-scan removed).

#define SCAN_CHUNK 2048

typedef _Float16 half8 __attribute__((ext_vector_type(8)));
typedef _Float16 half4 __attribute__((ext_vector_type(4)));
typedef float floatx4 __attribute__((ext_vector_type(4)));

// ---------------------------------------------------------------- generic scan
__global__ __launch_bounds__(256) void scan_partial_k(const int* __restrict__ cnt, int N,
                                                      int* __restrict__ bsum) {
  __shared__ int red[256];
  int b = blockIdx.x, t = threadIdx.x;
  int base = b * SCAN_CHUNK + t * 8;
  int s = 0;
#pragma unroll
  for (int i = 0; i < 8; ++i) {
    int idx = base + i;
    if (idx < N) s += cnt[idx];
  }
  red[t] = s;
  __syncthreads();
  for (int off = 128; off > 0; off >>= 1) {
    if (t < off) red[t] += red[t + off];
    __syncthreads();
  }
  if (t == 0) bsum[b] = red[0];
}

__global__ __launch_bounds__(64) void scan_bsum_k(int* __restrict__ bsum, int NB) {
  int lane = threadIdx.x;
  int per = (NB + 63) >> 6;
  int beg = lane * per;
  int end = min(beg + per, NB);
  int s = 0;
  for (int i = beg; i < end; ++i) s += bsum[i];
  int ps = s;
  for (int off = 1; off < 64; off <<= 1) {
    int u = __shfl_up(ps, off, 64);
    if (lane >= off) ps += u;
  }
  int run = ps - s;
  for (int i = beg; i < end; ++i) {
    int c = bsum[i];
    bsum[i] = run;
    run += c;
  }
}

__global__ __launch_bounds__(256) void scan_apply_k(const int* __restrict__ cnt,
                                                    const int* __restrict__ bsum_excl, int N,
                                                    int* __restrict__ rowptr,
                                                    int* __restrict__ cursor, int E) {
  __shared__ int wave_sums[4];
  int b = blockIdx.x, t = threadIdx.x;
  int base = b * SCAN_CHUNK + t * 8;
  int v[8];
  int s = 0;
#pragma unroll
  for (int i = 0; i < 8; ++i) {
    int idx = base + i;
    v[i] = (idx < N) ? cnt[idx] : 0;
    s += v[i];
  }
  int lane = t & 63, wave = t >> 6;
  int ps = s;
  for (int off = 1; off < 64; off <<= 1) {
    int u = __shfl_up(ps, off, 64);
    if (lane >= off) ps += u;
  }
  if (lane == 63) wave_sums[wave] = ps;
  __syncthreads();
  int woff = 0;
  for (int w = 0; w < 4; ++w)
    if (w < wave) woff += wave_sums[w];
  int excl = woff + (ps - s) + bsum_excl[b];
#pragma unroll
  for (int i = 0; i < 8; ++i) {
    int idx = base + i;
    if (idx < N) {
      rowptr[idx] = excl;
      cursor[idx] = excl;
      excl += v[i];
    }
  }
  if (b == 0 && t == 0) rowptr[N] = E;
}

// ------------------------------------------------- scan-sorted CSR build (new)
// Coarse bucket = dst >> 9 (512 nodes). Pack: (dst&511)<<17 | src (needs
// src < 2^17 -> N <= 131072; else fallback path below).
__global__ __launch_bounds__(256) void p1a_hist_k(const int* __restrict__ dst, int E, int G,
                                                  int B, int chunk, int* __restrict__ M) {
  __shared__ int h[256];
  int g = blockIdx.x, t = threadIdx.x;
  for (int i = t; i < B; i += 256) h[i] = 0;
  __syncthreads();
  int ebeg = g * chunk, eend = min(ebeg + chunk, E);
  for (int e = ebeg + t; e < eend; e += 256) atomicAdd(&h[dst[e] >> 9], 1);
  __syncthreads();
  for (int b = t; b < B; b += 256) M[(size_t)b * G + g] = h[b];
}

__global__ __launch_bounds__(256) void p1c_scatter_k(const int* __restrict__ src,
                                                     const int* __restrict__ dst, int E, int G,
                                                     int B, int chunk,
                                                     const int* __restrict__ scanned,
                                                     uint32_t* __restrict__ tmp) {
  __shared__ int off[256];
  int g = blockIdx.x, t = threadIdx.x;
  for (int b = t; b < B; b += 256) off[b] = scanned[(size_t)b * G + g];
  __syncthreads();
  int ebeg = g * chunk, eend = min(ebeg + chunk, E);
  for (int e = ebeg + t; e < eend; e += 256) {
    int d = dst[e];
    int b = d >> 9;
    int pos = atomicAdd(&off[b], 1);  // LDS cursor, private to this block
    tmp[pos] = ((uint32_t)(d & 511) << 17) | (uint32_t)src[e];
  }
}

// One workgroup per bucket: local histogram -> rowptr+dinv (coalesced), then
// LDS-cursor scatter of col within the bucket's ~33KB window (L2-resident).
__global__ __launch_bounds__(256) void p2_build_k(const uint32_t* __restrict__ tmp,
                                                  const int* __restrict__ scanned, int G, int N,
                                                  int E, int* __restrict__ rowptr,
                                                  int* __restrict__ col,
                                                  float* __restrict__ dinv) {
  __shared__ int hist[512];
  __shared__ int cur[512];
  __shared__ int wsum[4];
  int b = blockIdx.x, t = threadIdx.x;
  int node0 = b << 9;
  int nn = min(512, N - node0);
  int sbeg = scanned[(size_t)b * G];
  int send = scanned[(size_t)(b + 1) * G];
  for (int i = t; i < 512; i += 256) hist[i] = 0;
  __syncthreads();
  for (int e = sbeg + t; e < send; e += 256) atomicAdd(&hist[tmp[e] >> 17], 1);
  __syncthreads();
  int h0 = hist[2 * t], h1 = hist[2 * t + 1];
  int s = h0 + h1;
  int lane = t & 63, w = t >> 6;
  int ps = s;
  for (int o = 1; o < 64; o <<= 1) {
    int u = __shfl_up(ps, o, 64);
    if (lane >= o) ps += u;
  }
  if (lane == 63) wsum[w] = ps;
  __syncthreads();
  int woff = 0;
  for (int k = 0; k < 4; ++k)
    if (k < w) woff += wsum[k];
  int excl = sbeg + woff + (ps - s);
  if (2 * t < nn) {
    rowptr[node0 + 2 * t] = excl;
    cur[2 * t] = excl;
    dinv[node0 + 2 * t] = rsqrtf((float)(h0 + 1));
  }
  if (2 * t + 1 < nn) {
    rowptr[node0 + 2 * t + 1] = excl + h0;
    cur[2 * t + 1] = excl + h0;
    dinv[node0 + 2 * t + 1] = rsqrtf((float)(h1 + 1));
  }
  if (b == 0 && t == 0) rowptr[N] = E;
  __syncthreads();
  for (int e = sbeg + t; e < send; e += 256) {
    uint32_t u = tmp[e];
    int pos = atomicAdd(&cur[u >> 17], 1);
    col[pos] = (int)(u & 0x1FFFF);
  }
}

// ------------------------------------------------- fallback CSR build (N large)
__global__ __launch_bounds__(256) void count_edges_k(const int* __restrict__ dst, int E,
                                                     int* __restrict__ cnt) {
  int idx = blockIdx.x * blockDim.x + threadIdx.x;
  int stride = gridDim.x * blockDim.x;
  for (int e = idx; e < E; e += stride) atomicAdd(&cnt[dst[e]], 1);
}

__global__ __launch_bounds__(256) void dinv_k(const int* __restrict__ cnt,
                                              float* __restrict__ dinv, int N) {
  int i = blockIdx.x * blockDim.x + threadIdx.x;
  if (i < N) dinv[i] = rsqrtf((float)(cnt[i] + 1));
}

__global__ __launch_bounds__(256) void fill_k(const int* __restrict__ src,
                                              const int* __restrict__ dst, int E,
                                              int* __restrict__ cursor, int* __restrict__ col) {
  int idx = blockIdx.x * blockDim.x + threadIdx.x;
  int stride = gridDim.x * blockDim.x;
  for (int e = idx; e < E; e += stride) {
    int d = dst[e];
    int pos = atomicAdd(&cursor[d], 1);
    col[pos] = src[e];
  }
}

// ---------------------------------------------------------------- f16 MFMA GEMM
template <bool SIG, bool HIN, bool HOUT, int NT>
__global__ __launch_bounds__(256) void gemm_mfma_k(const void* __restrict__ Av,
                                                   const float* __restrict__ W,
                                                   const float* __restrict__ bias,
                                                   const float* __restrict__ scale,
                                                   void* __restrict__ outv, int N) {
  constexpr int NCOL = NT * 16;
  __shared__ __align__(16) _Float16 Af[64][136];
  __shared__ __align__(16) _Float16 Wf[NCOL][136];
  const int tid = threadIdx.x;
  const int r0 = blockIdx.x * 64;
  if (HIN) {
    const _Float16* A = (const _Float16*)Av;
    for (int idx = tid; idx < 64 * 16; idx += 256) {
      int row = idx >> 4;
      int c8 = (idx & 15) << 3;
      half8 v = {0, 0, 0, 0, 0, 0, 0, 0};
      int gr = r0 + row;
      if (gr < N) v = *(const half8*)(A + (size_t)gr * 128 + c8);
      *(half8*)&Af[row][c8] = v;
    }
  } else {
    const float* A = (const float*)Av;
    for (int idx = tid; idx < 64 * 32; idx += 256) {
      int row = idx >> 5;
      int c4 = (idx & 31) << 2;
      float4 v = make_float4(0.f, 0.f, 0.f, 0.f);
      int gr = r0 + row;
      if (gr < N) v = *(const float4*)(A + (size_t)gr * 128 + c4);
      Af[row][c4 + 0] = (_Float16)v.x;
      Af[row][c4 + 1] = (_Float16)v.y;
      Af[row][c4 + 2] = (_Float16)v.z;
      Af[row][c4 + 3] = (_Float16)v.w;
    }
  }
  for (int idx = tid; idx < 128 * (NCOL / 4); idx += 256) {
    int k = idx / (NCOL / 4);
    int n4 = (idx % (NCOL / 4)) << 2;
    float4 v = *(const float4*)(W + (size_t)k * NCOL + n4);
    Wf[n4 + 0][k] = (_Float16)v.x;
    Wf[n4 + 1][k] = (_Float16)v.y;
    Wf[n4 + 2][k] = (_Float16)v.z;
    Wf[n4 + 3][k] = (_Float16)v.w;
  }
  __syncthreads();
  const int w = tid >> 6, lane = tid & 63;
  const int m = lane & 15, q = lane >> 4;
  floatx4 acc[NT];
#pragma unroll
  for (int t = 0; t < NT; ++t) acc[t] = (floatx4){0.f, 0.f, 0.f, 0.f};
#pragma unroll
  for (int kt = 0; kt < 128; kt += 32) {
    half8 a = *(const half8*)&Af[w * 16 + m][kt + q * 8];
#pragma unroll
    for (int t = 0; t < NT; ++t) {
      half8 b = *(const half8*)&Wf[t * 16 + m][kt + q * 8];
      acc[t] = __builtin_amdgcn_mfma_f32_16x16x32_f16(a, b, acc[t], 0, 0, 0);
    }
  }
#pragma unroll
  for (int r = 0; r < 4; ++r) {
    int row = r0 + w * 16 + q * 4 + r;
    if (row >= N) continue;
    float sc = scale ? scale[row] : 1.f;
#pragma unroll
    for (int t = 0; t < NT; ++t) {
      int colg = t * 16 + m;
      float v = acc[t][r];
      if (bias) v += bias[colg];
      if (SIG) v = 1.f / (1.f + __expf(-v));
      v *= sc;
      if (HOUT)
        ((_Float16*)outv)[(size_t)row * NCOL + colg] = (_Float16)v;
      else
        ((float*)outv)[(size_t)row * NCOL + colg] = v;
    }
  }
}

// ---------------------------------------------------------------- aggregation
// xw (f16, pre-scaled by dinv[row]): out[i] = b + dinv[i]*(xw[i]+sum xw[src]).
// R5 form: 16 lanes x half8 cover the row; 4 edge slots; 4 gathers in flight.
__global__ __launch_bounds__(256) void agg128h_k(const _Float16* __restrict__ xw,
                                                 const int* __restrict__ rowptr,
                                                 const int* __restrict__ col,
                                                 const float* __restrict__ dinv,
                                                 const float* __restrict__ bias,
                                                 _Float16* __restrict__ out, int N) {
  int node = blockIdx.x * 4 + (threadIdx.x >> 6);
  if (node >= N) return;
  int lane = threadIdx.x & 63;
  int fl = lane & 15;
  int j = lane >> 4;
  int beg = rowptr[node];
  int end = rowptr[node + 1];
  const _Float16* base = xw + (size_t)fl * 8;
  float a[8] = {0.f, 0.f, 0.f, 0.f, 0.f, 0.f, 0.f, 0.f};
  int e = beg + j;
  for (; e + 12 < end; e += 16) {
    int s0 = col[e], s1 = col[e + 4], s2 = col[e + 8], s3 = col[e + 12];
    half8 v0 = *(const half8*)(base + (size_t)s0 * 128);
    half8 v1 = *(const half8*)(base + (size_t)s1 * 128);
    half8 v2 = *(const half8*)(base + (size_t)s2 * 128);
    half8 v3 = *(const half8*)(base + (size_t)s3 * 128);
#pragma unroll
    for (int f = 0; f < 8; ++f)
      a[f] += ((float)v0[f] + (float)v1[f]) + ((float)v2[f] + (float)v3[f]);
  }
  for (; e < end; e += 4) {
    half8 v = *(const half8*)(base + (size_t)col[e] * 128);
#pragma unroll
    for (int f = 0; f < 8; ++f) a[f] += (float)v[f];
  }
  if (j == 0) {
    half8 v = *(const half8*)(base + (size_t)node * 128);
#pragma unroll
    for (int f = 0; f < 8; ++f) a[f] += (float)v[f];
  }
#pragma unroll
  for (int f = 0; f < 8; ++f) {
    a[f] += __shfl_xor(a[f], 16, 64);
    a[f] += __shfl_xor(a[f], 32, 64);
  }
  if (j == 0) {
    float di = dinv[node];
    float4 b0 = *(const float4*)(bias + fl * 8);
    float4 b1 = *(const float4*)(bias + fl * 8 + 4);
    half8 o;
    o[0] = (_Float16)fmaf(a[0], di, b0.x);
    o[1] = (_Float16)fmaf(a[1], di, b0.y);
    o[2] = (_Float16)fmaf(a[2], di, b0.z);
    o[3] = (_Float16)fmaf(a[3], di, b0.w);
    o[4] = (_Float16)fmaf(a[4], di, b1.x);
    o[5] = (_Float16)fmaf(a[5], di, b1.y);
    o[6] = (_Float16)fmaf(a[6], di, b1.z);
    o[7] = (_Float16)fmaf(a[7], di, b1.w);
    *(half8*)(out + (size_t)node * 128 + fl * 8) = o;
  }
}

__global__ __launch_bounds__(256) void agg16_k(const float* __restrict__ xw,
                                               const int* __restrict__ rowptr,
                                               const int* __restrict__ col,
                                               const float* __restrict__ dinv,
                                               const float* __restrict__ bias,
                                               float* __restrict__ out, int N) {
  int node = blockIdx.x * 4 + (threadIdx.x >> 6);
  if (node >= N) return;
  int lane = threadIdx.x & 63;
  int f = lane & 15;
  int j = lane >> 4;
  int beg = rowptr[node];
  int end = rowptr[node + 1];
  float acc = 0.f;
  for (int e = beg + j; e < end; e += 4) {
    acc += xw[(size_t)col[e] * 16 + f];
  }
  acc += __shfl_xor(acc, 16, 64);
  acc += __shfl_xor(acc, 32, 64);
  float o = fmaf(acc + xw[(size_t)node * 16 + f], dinv[node], bias[f]);
  if (j == 0) out[(size_t)node * 16 + f] = o;
}

// ---------------------------------------------------------------- launch
extern "C" void kernel_launch(void* const* d_in, const int* in_sizes, int n_in,
                              void* d_out, int out_size, void* d_ws, size_t ws_size,
                              hipStream_t stream) {
  const int* adj = (const int*)d_in[0];
  const float* X = (const float*)d_in[1];
  const float* fc1_W = (const float*)d_in[2];
  const float* fc1_b = (const float*)d_in[3];
  const float* fc2_W = (const float*)d_in[4];
  const float* fc2_b = (const float*)d_in[5];
  const float* gcn_W = (const float*)d_in[6];
  const float* gcn_b = (const float*)d_in[7];
  const float* assign_W = (const float*)d_in[8];
  const float* assign_b = (const float*)d_in[9];
  const int E = in_sizes[0] / 2;
  const int N = in_sizes[1] / 128;
  const int* src = adj;
  const int* dst = adj + E;

  char* ws = (char*)d_ws;
  size_t off = 0;
  auto alloc = [&](size_t bytes) {
    void* p = ws + off;
    off = (off + bytes + 511) & ~(size_t)511;
    return p;
  };
  const int G = 256;
  const int B = (N + 511) >> 9;
  const int L = B * G;
  _Float16* Ph = (_Float16*)alloc((size_t)N * 128 * 2);  // 25.6 MB
  _Float16* Qh = (_Float16*)alloc((size_t)N * 128 * 2);  // 25.6 MB
  float* dinv = (float*)alloc((size_t)N * 4);
  int* rowptr = (int*)alloc((size_t)(N + 1) * 4);
  int* col = (int*)alloc((size_t)E * 4);
  uint32_t* tmp = (uint32_t*)alloc((size_t)E * 4);
  int* M = (int*)alloc((size_t)L * 4);
  int* scanned = (int*)alloc((size_t)(L + 1) * 4);
  int* scanscratch = (int*)alloc((size_t)L * 4);
  int* bsum = (int*)alloc(4096);
  int* cnt = (int*)alloc((size_t)N * 4);     // fallback path only
  int* cursor = (int*)alloc((size_t)N * 4);  // fallback path only
  float* S = (float*)Ph;  // assign xw [N,16] fp32 reuses Ph

  if (N <= (1 << 17)) {
    const int chunk = (E + G - 1) / G;
    const int NBL = (L + SCAN_CHUNK - 1) / SCAN_CHUNK;
    p1a_hist_k<<<G, 256, 0, stream>>>(dst, E, G, B, chunk, M);
    scan_partial_k<<<NBL, 256, 0, stream>>>(M, L, bsum);
    scan_bsum_k<<<1, 64, 0, stream>>>(bsum, NBL);
    scan_apply_k<<<NBL, 256, 0, stream>>>(M, bsum, L, scanned, scanscratch, E);
    p1c_scatter_k<<<G, 256, 0, stream>>>(src, dst, E, G, B, chunk, scanned, tmp);
    p2_build_k<<<B, 256, 0, stream>>>(tmp, scanned, G, N, E, rowptr, col, dinv);
  } else {
    const int NB = (N + SCAN_CHUNK - 1) / SCAN_CHUNK;
    hipMemsetAsync(cnt, 0, (size_t)N * 4, stream);
    count_edges_k<<<2048, 256, 0, stream>>>(dst, E, cnt);
    dinv_k<<<(N + 255) / 256, 256, 0, stream>>>(cnt, dinv, N);
    scan_partial_k<<<NB, 256, 0, stream>>>(cnt, N, bsum);
    scan_bsum_k<<<1, 64, 0, stream>>>(bsum, NB);
    scan_apply_k<<<NB, 256, 0, stream>>>(cnt, bsum, N, rowptr, cursor, E);
    fill_k<<<2048, 256, 0, stream>>>(src, dst, E, cursor, col);
  }

  int gb = (N + 63) / 64;
  int ab = (N + 3) / 4;
  gemm_mfma_k<true, false, true, 8><<<gb, 256, 0, stream>>>(X, fc1_W, fc1_b, nullptr, Ph, N);
  gemm_mfma_k<true, true, true, 8><<<gb, 256, 0, stream>>>(Ph, fc2_W, fc2_b, nullptr, Qh, N);
  for (int l = 0; l < 3; ++l) {
    gemm_mfma_k<false, true, true, 8><<<gb, 256, 0, stream>>>(
        Qh, gcn_W + (size_t)l * 128 * 128, nullptr, dinv, Ph, N);
    agg128h_k<<<ab, 256, 0, stream>>>(Ph, rowptr, col, dinv, gcn_b + (size_t)l * 128, Qh, N);
  }
  gemm_mfma_k<false, true, false, 1><<<gb, 256, 0, stream>>>(Qh, assign_W, nullptr, dinv, S, N);
  agg16_k<<<ab, 256, 0, stream>>>(S, rowptr, col, dinv, assign_b, (float*)d_out, N);
}